// Round 1
// baseline (251225.659 us; speedup 1.0000x reference)
//
#include <hip/hip_runtime.h>

#define T_STEPS 4096
#define HDIM 1024

typedef __bf16 bf16x8 __attribute__((ext_vector_type(8)));
typedef float f32x4 __attribute__((ext_vector_type(4)));

__device__ __forceinline__ unsigned short f2bf(float x) {
  unsigned u = __builtin_bit_cast(unsigned, x);
  u += 0x7fffu + ((u >> 16) & 1u);   // RNE
  return (unsigned short)(u >> 16);
}
__device__ __forceinline__ float bf2f(unsigned short b) {
  unsigned u = ((unsigned)b) << 16;
  return __builtin_bit_cast(float, u);
}

// ---------------------------------------------------------------------------
// Kernel 1: build xs_bf16 [2][4096][2048] from res_for / res_back (with the
// reference's concat + reversal folded into the indexing).
// ---------------------------------------------------------------------------
__global__ __launch_bounds__(256) void build_xs(
    const float* __restrict__ rf, const float* __restrict__ rb,
    unsigned short* __restrict__ xs) {
  int idx = blockIdx.x * 256 + threadIdx.x;   // one thread per 4 elems
  int e = idx * 4;                             // flat elem index, < 2*4096*2048
  int f = e & 2047;
  int td = e >> 11;
  int t = td & 4095;
  int d = td >> 12;
  bool lower = f < 1024;
  int f2 = f & 1023;
  int trow;
  if (d == 0) trow = lower ? t : (4095 - t);
  else        trow = lower ? (4095 - t) : t;
  const float* src = (lower ? rf : rb) + trow * 1024 + f2;
  float4 v = *(const float4*)src;
  unsigned short o0 = f2bf(v.x), o1 = f2bf(v.y), o2 = f2bf(v.z), o3 = f2bf(v.w);
  ushort4 o = make_ushort4(o0, o1, o2, o3);
  *(ushort4*)(xs + e) = o;
}

// ---------------------------------------------------------------------------
// Kernel 2: wxT_bf16 [4096 g][2048 f] = transpose of w[:2048] (so GEMM B-tiles
// have k contiguous per output column). LDS tile transpose, coalesced both ways.
// ---------------------------------------------------------------------------
__global__ __launch_bounds__(256) void transpose_wx(
    const float* __restrict__ w, unsigned short* __restrict__ wxT) {
  __shared__ float tile[64][65];
  int bid = blockIdx.x;          // 2048 = 32 (f) * 64 (g)
  int bf_ = bid / 64;            // f tile
  int bg = bid % 64;             // g tile
  int f0 = bf_ * 64, g0 = bg * 64;
  int tid = threadIdx.x;
#pragma unroll
  for (int s = 0; s < 16; ++s) {
    int idx = s * 256 + tid;
    int fl = idx >> 6, gl = idx & 63;
    tile[fl][gl] = w[(size_t)(f0 + fl) * 4096 + g0 + gl];
  }
  __syncthreads();
#pragma unroll
  for (int s = 0; s < 16; ++s) {
    int idx = s * 256 + tid;
    int gl = idx >> 6, fl = idx & 63;
    wxT[(size_t)(g0 + gl) * 2048 + f0 + fl] = f2bf(tile[fl][gl]);
  }
}

// ---------------------------------------------------------------------------
// Kernel 3: zx = xs @ wx  -> bf16 [8192][4096].
// 128x128 tile, BK=32, 4 waves (2x2 of 64x64), mfma_f32_16x16x32_bf16.
// Both LDS tiles are [128 rows][32 k] bf16 with XOR swizzle P = L ^ ((row&7)<<4)
// applied on write AND read (reg-staged writes, so both sides can swizzle).
// ---------------------------------------------------------------------------
__global__ __launch_bounds__(256) void gemm_zx(
    const unsigned short* __restrict__ xs, const unsigned short* __restrict__ wxT,
    unsigned short* __restrict__ zxo) {
  __shared__ uint4 lds[1024];   // A: bytes [0,8192), B: [8192,16384)
  char* ldsb = (char*)lds;
  int bid = blockIdx.x;
  int by = bid >> 5;            // 0..63  (M tiles)
  int bx = bid & 31;            // 0..31  (N tiles)
  int tid = threadIdx.x, lane = tid & 63, wid = tid >> 6;
  int wr = wid >> 1, wc = wid & 1;
  const int arow0 = by * 128, bcol0 = bx * 128;

  f32x4 acc[4][4] = {};

  for (int kt = 0; kt < 64; ++kt) {
    int k0 = kt * 32;
#pragma unroll
    for (int s = 0; s < 2; ++s) {
      int c = tid + 256 * s;                 // chunk 0..511
      int L = c * 16;
      int P = L ^ (((L >> 6) & 7) << 4);
      int row = c >> 2, ko = (c & 3) * 8;
      uint4 av = *(const uint4*)(xs  + (size_t)(arow0 + row) * 2048 + k0 + ko);
      uint4 bv = *(const uint4*)(wxT + (size_t)(bcol0 + row) * 2048 + k0 + ko);
      *(uint4*)(ldsb + P) = av;
      *(uint4*)(ldsb + 8192 + P) = bv;
    }
    __syncthreads();

    bf16x8 afr[4], bfr[4];
#pragma unroll
    for (int i = 0; i < 4; ++i) {
      int arow = wr * 64 + i * 16 + (lane & 15);
      int L = arow * 64 + (lane >> 4) * 16;
      int P = L ^ ((arow & 7) << 4);
      afr[i] = *(bf16x8*)(ldsb + P);
      int brow = wc * 64 + i * 16 + (lane & 15);
      int L2 = brow * 64 + (lane >> 4) * 16;
      int P2 = L2 ^ ((brow & 7) << 4);
      bfr[i] = *(bf16x8*)(ldsb + 8192 + P2);
    }
#pragma unroll
    for (int mi = 0; mi < 4; ++mi)
#pragma unroll
      for (int ni = 0; ni < 4; ++ni)
        acc[mi][ni] = __builtin_amdgcn_mfma_f32_16x16x32_bf16(
            afr[mi], bfr[ni], acc[mi][ni], 0, 0, 0);
    __syncthreads();
  }

  // epilogue: C/D layout col = lane&15, row = (lane>>4)*4 + r  [m89 verified]
#pragma unroll
  for (int mi = 0; mi < 4; ++mi)
#pragma unroll
    for (int ni = 0; ni < 4; ++ni)
#pragma unroll
      for (int r = 0; r < 4; ++r) {
        int rrow = arow0 + wr * 64 + mi * 16 + (lane >> 4) * 4 + r;
        int col  = bcol0 + wc * 64 + ni * 16 + (lane & 15);
        zxo[(size_t)rrow * 4096 + col] = f2bf(acc[mi][ni][r]);
      }
}

// ---------------------------------------------------------------------------
// Kernel 4: persistent recurrent LSTM. 128 blocks (64/dir) x 1024 threads.
// Block owns 16 h-rows (j) = 64 gate-columns. wave = k-slice, lane = column.
// W_h in f32 registers (64/thread). h broadcast via d_out + atomic counter.
// ---------------------------------------------------------------------------
__device__ __forceinline__ float sigm(float x) {
  return 1.0f / (1.0f + __expf(-x));
}
__device__ __forceinline__ float tanh_fast(float x) {
  float e = __expf(-2.0f * x);
  return (1.0f - e) / (1.0f + e);
}

__global__ __launch_bounds__(1024, 4) void lstm_rec(
    const unsigned short* __restrict__ zx,  // [2][4096][4096] bf16
    const float* __restrict__ w,            // [3072][4096] f32 (w_h = rows 2048+)
    float* __restrict__ hout,               // d_out [2][4096][1024] f32
    unsigned* __restrict__ cnt) {           // per-dir counters, 128B apart
  __shared__ float4 h4[256];                // h staging (1024 f32)
  __shared__ float part[16][64];
  __shared__ float zl[64];

  int bid = blockIdx.x;
  int dir = bid >> 6;
  int bslot = bid & 63;
  int jbase = bslot << 4;                   // 16 j's per block
  int tid = threadIdx.x;
  int wave = tid >> 6;                      // k-slice: wave*64..+63
  int lane = tid & 63;                      // column c: jj = c&15, gate = c>>4
  int jj = lane & 15, g = lane >> 4;
  int gcol = (g << 10) + jbase + jj;

  // preload W_h slice: w[(2048 + wave*64 + p)][gcol], p = 0..63 (f32, exact)
  float wreg[64];
#pragma unroll
  for (int p = 0; p < 64; ++p)
    wreg[p] = w[(size_t)(2048 + wave * 64 + p) * 4096 + gcol];

  float* h_lds = (float*)h4;
  float c_reg = 0.0f;
  const unsigned short* zrow = zx + (size_t)dir * T_STEPS * 4096;
  float* hrow = hout + (size_t)dir * T_STEPS * HDIM;
  unsigned* mycnt = cnt + dir * 32;

  for (int t = 0; t < T_STEPS; ++t) {
    // prefetch zx_t (independent of h)
    float zxv = 0.0f;
    if (tid < 64)
      zxv = bf2f(zrow[(size_t)t * 4096 + ((tid >> 4) << 10) + jbase + (tid & 15)]);

    // stage h_{t-1} into LDS
    float hv = 0.0f;
    if (t > 0) hv = hrow[(size_t)(t - 1) * HDIM + tid];
    h_lds[tid] = hv;
    __syncthreads();

    // per-wave partial dot: this wave's 64-k slice, lane's column
    const float4* hw = h4 + wave * 16;
    float a0 = 0.f, a1 = 0.f, a2 = 0.f, a3 = 0.f;
#pragma unroll
    for (int q = 0; q < 16; ++q) {
      float4 x = hw[q];
      a0 = fmaf(wreg[4 * q + 0], x.x, a0);
      a1 = fmaf(wreg[4 * q + 1], x.y, a1);
      a2 = fmaf(wreg[4 * q + 2], x.z, a2);
      a3 = fmaf(wreg[4 * q + 3], x.w, a3);
    }
    part[wave][lane] = (a0 + a1) + (a2 + a3);
    __syncthreads();

    // reduce 16 wave-partials per column, add zx
    if (tid < 64) {
      float z = zxv;
#pragma unroll
      for (int q = 0; q < 16; ++q) z += part[q][tid];
      zl[tid] = z;
    }
    __syncthreads();

    // gates + state update (16 threads; c stays in-register, f32)
    if (tid < 16) {
      float zi = zl[tid], zc = zl[16 + tid], zf = zl[32 + tid], zo = zl[48 + tid];
      float i = sigm(zi);
      float ci = tanh_fast(zc);
      float f = sigm(zf + 1.0f);          // FORGET_BIAS
      float cs = fmaf(f, c_reg, i * ci);
      cs = fminf(3.0f, fmaxf(-3.0f, cs)); // CELL_CLIP
      c_reg = cs;
      float o = sigm(zo);
      hrow[(size_t)t * HDIM + jbase + tid] = o * tanh_fast(cs);
    }
    __threadfence();      // release h stores (device scope)
    __syncthreads();

    if (t + 1 < T_STEPS) {
      if (tid == 0) {
        __hip_atomic_fetch_add(mycnt, 1u, __ATOMIC_RELEASE, __HIP_MEMORY_SCOPE_AGENT);
        unsigned target = 64u * (unsigned)(t + 1);
        while (__hip_atomic_load(mycnt, __ATOMIC_RELAXED, __HIP_MEMORY_SCOPE_AGENT) < target) {
        }
      }
      __syncthreads();
      __threadfence();    // acquire side before next-step h loads
    }
  }
}

// ---------------------------------------------------------------------------
// launch
// ---------------------------------------------------------------------------
extern "C" void kernel_launch(void* const* d_in, const int* in_sizes, int n_in,
                              void* d_out, int out_size, void* d_ws, size_t ws_size,
                              hipStream_t stream) {
  const float* rf = (const float*)d_in[0];   // res_for_1  [1][4096][1024]
  const float* rb = (const float*)d_in[1];   // res_back_1 [1][4096][1024]
  const float* w  = (const float*)d_in[2];   // w [3072][4096]
  float* out = (float*)d_out;                // [2][4096][1024]

  char* ws = (char*)d_ws;
  unsigned short* zx  = (unsigned short*)ws;                         // 64 MiB
  unsigned*       cnt = (unsigned*)(ws + (64u << 20));               // 256 B
  unsigned short* xs  = (unsigned short*)(ws + (64u << 20) + 4096);  // 32 MiB
  unsigned short* wxT = (unsigned short*)(ws + (64u << 20) + 4096 + (32u << 20)); // 16 MiB

  hipMemsetAsync(cnt, 0, 256, stream);

  build_xs<<<16384, 256, 0, stream>>>(rf, rb, xs);
  transpose_wx<<<2048, 256, 0, stream>>>(w, wxT);
  gemm_zx<<<2048, 256, 0, stream>>>(xs, wxT, zx);
  lstm_rec<<<128, 1024, 0, stream>>>(zx, w, out, cnt);
}

// Round 2
// 9669.183 us; speedup vs baseline: 25.9821x; 25.9821x over previous
//
#include <hip/hip_runtime.h>

#define T_STEPS 4096
#define HDIM 1024

typedef __bf16 bf16x8 __attribute__((ext_vector_type(8)));
typedef float f32x4 __attribute__((ext_vector_type(4)));

__device__ __forceinline__ unsigned short f2bf(float x) {
  unsigned u = __builtin_bit_cast(unsigned, x);
  u += 0x7fffu + ((u >> 16) & 1u);   // RNE
  return (unsigned short)(u >> 16);
}
__device__ __forceinline__ float bf2f(unsigned short b) {
  unsigned u = ((unsigned)b) << 16;
  return __builtin_bit_cast(float, u);
}

// ---------------------------------------------------------------------------
// Kernel 1: build xs_bf16 [2][4096][2048] from res_for / res_back (with the
// reference's concat + reversal folded into the indexing).
// ---------------------------------------------------------------------------
__global__ __launch_bounds__(256) void build_xs(
    const float* __restrict__ rf, const float* __restrict__ rb,
    unsigned short* __restrict__ xs) {
  int idx = blockIdx.x * 256 + threadIdx.x;   // one thread per 4 elems
  int e = idx * 4;                             // flat elem index, < 2*4096*2048
  int f = e & 2047;
  int td = e >> 11;
  int t = td & 4095;
  int d = td >> 12;
  bool lower = f < 1024;
  int f2 = f & 1023;
  int trow;
  if (d == 0) trow = lower ? t : (4095 - t);
  else        trow = lower ? (4095 - t) : t;
  const float* src = (lower ? rf : rb) + trow * 1024 + f2;
  float4 v = *(const float4*)src;
  unsigned short o0 = f2bf(v.x), o1 = f2bf(v.y), o2 = f2bf(v.z), o3 = f2bf(v.w);
  ushort4 o = make_ushort4(o0, o1, o2, o3);
  *(ushort4*)(xs + e) = o;
}

// ---------------------------------------------------------------------------
// Kernel 2: wxT_bf16 [4096 g][2048 f] = transpose of w[:2048].
// ---------------------------------------------------------------------------
__global__ __launch_bounds__(256) void transpose_wx(
    const float* __restrict__ w, unsigned short* __restrict__ wxT) {
  __shared__ float tile[64][65];
  int bid = blockIdx.x;          // 2048 = 32 (f) * 64 (g)
  int bf_ = bid / 64;            // f tile
  int bg = bid % 64;             // g tile
  int f0 = bf_ * 64, g0 = bg * 64;
  int tid = threadIdx.x;
#pragma unroll
  for (int s = 0; s < 16; ++s) {
    int idx = s * 256 + tid;
    int fl = idx >> 6, gl = idx & 63;
    tile[fl][gl] = w[(size_t)(f0 + fl) * 4096 + g0 + gl];
  }
  __syncthreads();
#pragma unroll
  for (int s = 0; s < 16; ++s) {
    int idx = s * 256 + tid;
    int gl = idx >> 6, fl = idx & 63;
    wxT[(size_t)(g0 + gl) * 2048 + f0 + fl] = f2bf(tile[fl][gl]);
  }
}

// ---------------------------------------------------------------------------
// Kernel 3: zx = xs @ wx  -> bf16 [8192][4096].
// 128x128 tile, BK=32, 4 waves (2x2 of 64x64), mfma_f32_16x16x32_bf16.
// XOR-swizzled LDS (write AND read side, reg-staged writes).
// ---------------------------------------------------------------------------
__global__ __launch_bounds__(256) void gemm_zx(
    const unsigned short* __restrict__ xs, const unsigned short* __restrict__ wxT,
    unsigned short* __restrict__ zxo) {
  __shared__ uint4 lds[1024];   // A: bytes [0,8192), B: [8192,16384)
  char* ldsb = (char*)lds;
  int bid = blockIdx.x;
  int by = bid >> 5;            // 0..63  (M tiles)
  int bx = bid & 31;            // 0..31  (N tiles)
  int tid = threadIdx.x, lane = tid & 63, wid = tid >> 6;
  int wr = wid >> 1, wc = wid & 1;
  const int arow0 = by * 128, bcol0 = bx * 128;

  f32x4 acc[4][4] = {};

  for (int kt = 0; kt < 64; ++kt) {
    int k0 = kt * 32;
#pragma unroll
    for (int s = 0; s < 2; ++s) {
      int c = tid + 256 * s;                 // chunk 0..511
      int L = c * 16;
      int P = L ^ (((L >> 6) & 7) << 4);
      int row = c >> 2, ko = (c & 3) * 8;
      uint4 av = *(const uint4*)(xs  + (size_t)(arow0 + row) * 2048 + k0 + ko);
      uint4 bv = *(const uint4*)(wxT + (size_t)(bcol0 + row) * 2048 + k0 + ko);
      *(uint4*)(ldsb + P) = av;
      *(uint4*)(ldsb + 8192 + P) = bv;
    }
    __syncthreads();

    bf16x8 afr[4], bfr[4];
#pragma unroll
    for (int i = 0; i < 4; ++i) {
      int arow = wr * 64 + i * 16 + (lane & 15);
      int L = arow * 64 + (lane >> 4) * 16;
      int P = L ^ ((arow & 7) << 4);
      afr[i] = *(bf16x8*)(ldsb + P);
      int brow = wc * 64 + i * 16 + (lane & 15);
      int L2 = brow * 64 + (lane >> 4) * 16;
      int P2 = L2 ^ ((brow & 7) << 4);
      bfr[i] = *(bf16x8*)(ldsb + 8192 + P2);
    }
#pragma unroll
    for (int mi = 0; mi < 4; ++mi)
#pragma unroll
      for (int ni = 0; ni < 4; ++ni)
        acc[mi][ni] = __builtin_amdgcn_mfma_f32_16x16x32_bf16(
            afr[mi], bfr[ni], acc[mi][ni], 0, 0, 0);
    __syncthreads();
  }

  // epilogue: C/D layout col = lane&15, row = (lane>>4)*4 + r  [m89 verified]
#pragma unroll
  for (int mi = 0; mi < 4; ++mi)
#pragma unroll
    for (int ni = 0; ni < 4; ++ni)
#pragma unroll
      for (int r = 0; r < 4; ++r) {
        int rrow = arow0 + wr * 64 + mi * 16 + (lane >> 4) * 4 + r;
        int col  = bcol0 + wc * 64 + ni * 16 + (lane & 15);
        zxo[(size_t)rrow * 4096 + col] = f2bf(acc[mi][ni][r]);
      }
}

// ---------------------------------------------------------------------------
// Kernel 4: persistent recurrent LSTM. 128 blocks (64/dir) x 1024 threads.
// Cross-block sync: per-block flag + relaxed agent-scope (sc0 sc1) accesses.
// NO __threadfence / release atomics in the steady state (those emit
// buffer_wbl2/buffer_inv = full-L2 maintenance, measured 61 us/step in R1).
// ---------------------------------------------------------------------------
__device__ __forceinline__ float sigm(float x) {
  return 1.0f / (1.0f + __expf(-x));
}
__device__ __forceinline__ float tanh_fast(float x) {
  float e = __expf(-2.0f * x);
  return (1.0f - e) / (1.0f + e);
}

__global__ __launch_bounds__(1024, 4) void lstm_rec(
    const unsigned short* __restrict__ zx,  // [2][4096][4096] bf16
    const float* __restrict__ w,            // [3072][4096] f32 (w_h = rows 2048+)
    float* __restrict__ hout,               // d_out [2][4096][1024] f32
    unsigned* __restrict__ flags) {         // [2][64] step flags, 64B stride
  __shared__ float4 h4[256];                // h staging (1024 f32)
  __shared__ float part[16][64];
  __shared__ float zl[64];

  int bid = blockIdx.x;
  int dir = bid >> 6;
  int bslot = bid & 63;
  int jbase = bslot << 4;                   // 16 j's per block
  int tid = threadIdx.x;
  int wave = tid >> 6;                      // k-slice: wave*64..+63
  int lane = tid & 63;                      // column c: jj = c&15, gate = c>>4
  int jj = lane & 15, g = lane >> 4;
  int gcol = (g << 10) + jbase + jj;

  // preload W_h slice: w[(2048 + wave*64 + p)][gcol], p = 0..63 (f32, exact)
  float wreg[64];
#pragma unroll
  for (int p = 0; p < 64; ++p)
    wreg[p] = w[(size_t)(2048 + wave * 64 + p) * 4096 + gcol];

  float* h_lds = (float*)h4;
  float c_reg = 0.0f;
  const unsigned short* zrow = zx + (size_t)dir * T_STEPS * 4096;
  float* hrow = hout + (size_t)dir * T_STEPS * HDIM;
  unsigned* fbase = flags + dir * 64 * 16;      // this dir's 64 flags, 64B apart
  unsigned* myflag = fbase + bslot * 16;

  for (int t = 0; t < T_STEPS; ++t) {
    // prefetch zx_t (independent of h)
    float zxv = 0.0f;
    if (tid < 64)
      zxv = bf2f(zrow[(size_t)t * 4096 + ((tid >> 4) << 10) + jbase + (tid & 15)]);

    // wait for step t-1 from all 64 blocks of this dir, then load h_{t-1}
    float hv = 0.0f;
    if (t > 0) {
      if (wave == 0) {
        const unsigned* fl = fbase + lane * 16;
        unsigned target = (unsigned)t;
        while (true) {
          unsigned v = __hip_atomic_load(fl, __ATOMIC_RELAXED, __HIP_MEMORY_SCOPE_AGENT);
          if (__ballot(v >= target) == ~0ull) break;
        }
      }
      __syncthreads();
      asm volatile("" ::: "memory");
      hv = __hip_atomic_load(&hrow[(size_t)(t - 1) * HDIM + tid],
                             __ATOMIC_RELAXED, __HIP_MEMORY_SCOPE_AGENT);
    }
    h_lds[tid] = hv;
    __syncthreads();

    // per-wave partial dot: this wave's 64-k slice, lane's column
    const float4* hw = h4 + wave * 16;
    float a0 = 0.f, a1 = 0.f, a2 = 0.f, a3 = 0.f;
#pragma unroll
    for (int q = 0; q < 16; ++q) {
      float4 x = hw[q];
      a0 = fmaf(wreg[4 * q + 0], x.x, a0);
      a1 = fmaf(wreg[4 * q + 1], x.y, a1);
      a2 = fmaf(wreg[4 * q + 2], x.z, a2);
      a3 = fmaf(wreg[4 * q + 3], x.w, a3);
    }
    part[wave][lane] = (a0 + a1) + (a2 + a3);
    __syncthreads();

    // wave 0: reduce 16 wave-partials per column, gates, h store, flag store
    if (wave == 0) {
      float z = zxv;
#pragma unroll
      for (int q = 0; q < 16; ++q) z += part[q][lane];
      zl[lane] = z;                      // wave-coherent LDS, no barrier needed
      if (lane < 16) {
        float zi = zl[lane], zc = zl[16 + lane], zf = zl[32 + lane], zo = zl[48 + lane];
        float i = sigm(zi);
        float ci = tanh_fast(zc);
        float f = sigm(zf + 1.0f);          // FORGET_BIAS
        float cs = fmaf(f, c_reg, i * ci);
        cs = fminf(3.0f, fmaxf(-3.0f, cs)); // CELL_CLIP
        c_reg = cs;
        float o = sigm(zo);
        // write-through to IF (coherent point) — per-access, no cache fence
        __hip_atomic_store(&hrow[(size_t)t * HDIM + jbase + lane], o * tanh_fast(cs),
                           __ATOMIC_RELAXED, __HIP_MEMORY_SCOPE_AGENT);
      }
      if (t + 1 < T_STEPS) {
        asm volatile("s_waitcnt vmcnt(0)" ::: "memory");  // h stores reached IF
        if (lane == 0)
          __hip_atomic_store(myflag, (unsigned)(t + 1),
                             __ATOMIC_RELAXED, __HIP_MEMORY_SCOPE_AGENT);
      }
    }
    // (no barrier here: next iteration's poll-__syncthreads orders everyone)
  }
}

// ---------------------------------------------------------------------------
// launch
// ---------------------------------------------------------------------------
extern "C" void kernel_launch(void* const* d_in, const int* in_sizes, int n_in,
                              void* d_out, int out_size, void* d_ws, size_t ws_size,
                              hipStream_t stream) {
  const float* rf = (const float*)d_in[0];   // res_for_1  [1][4096][1024]
  const float* rb = (const float*)d_in[1];   // res_back_1 [1][4096][1024]
  const float* w  = (const float*)d_in[2];   // w [3072][4096]
  float* out = (float*)d_out;                // [2][4096][1024]

  char* ws = (char*)d_ws;
  unsigned short* zx  = (unsigned short*)ws;                          // 64 MiB
  unsigned*     flags = (unsigned*)(ws + (64u << 20));                // 8 KiB (64 KiB reserved)
  unsigned short* xs  = (unsigned short*)(ws + (64u << 20) + (64u << 10));  // 32 MiB
  unsigned short* wxT = (unsigned short*)(ws + (64u << 20) + (64u << 10) + (32u << 20)); // 16 MiB

  hipMemsetAsync(flags, 0, 64 << 10, stream);

  build_xs<<<16384, 256, 0, stream>>>(rf, rb, xs);
  transpose_wx<<<2048, 256, 0, stream>>>(w, wxT);
  gemm_zx<<<2048, 256, 0, stream>>>(xs, wxT, zx);
  lstm_rec<<<128, 1024, 0, stream>>>(zx, w, out, flags);
}

// Round 3
// 7618.534 us; speedup vs baseline: 32.9756x; 1.2692x over previous
//
#include <hip/hip_runtime.h>

#define T_STEPS 4096
#define HDIM 1024

typedef __bf16 bf16x8 __attribute__((ext_vector_type(8)));
typedef float f32x4 __attribute__((ext_vector_type(4)));

__device__ __forceinline__ unsigned short f2bf(float x) {
  unsigned u = __builtin_bit_cast(unsigned, x);
  u += 0x7fffu + ((u >> 16) & 1u);   // RNE
  return (unsigned short)(u >> 16);
}
__device__ __forceinline__ float bf2f(unsigned short b) {
  unsigned u = ((unsigned)b) << 16;
  return __builtin_bit_cast(float, u);
}

// ---------------------------------------------------------------------------
// Kernel 1: build xs_bf16 [2][4096][2048] from res_for / res_back.
// ---------------------------------------------------------------------------
__global__ __launch_bounds__(256) void build_xs(
    const float* __restrict__ rf, const float* __restrict__ rb,
    unsigned short* __restrict__ xs) {
  int idx = blockIdx.x * 256 + threadIdx.x;   // one thread per 4 elems
  int e = idx * 4;
  int f = e & 2047;
  int td = e >> 11;
  int t = td & 4095;
  int d = td >> 12;
  bool lower = f < 1024;
  int f2 = f & 1023;
  int trow;
  if (d == 0) trow = lower ? t : (4095 - t);
  else        trow = lower ? (4095 - t) : t;
  const float* src = (lower ? rf : rb) + trow * 1024 + f2;
  float4 v = *(const float4*)src;
  ushort4 o = make_ushort4(f2bf(v.x), f2bf(v.y), f2bf(v.z), f2bf(v.w));
  *(ushort4*)(xs + e) = o;
}

// ---------------------------------------------------------------------------
// Kernel 2: wxT_bf16 [4096 g][2048 f] = transpose of w[:2048].
// ---------------------------------------------------------------------------
__global__ __launch_bounds__(256) void transpose_wx(
    const float* __restrict__ w, unsigned short* __restrict__ wxT) {
  __shared__ float tile[64][65];
  int bid = blockIdx.x;          // 2048 = 32 (f) * 64 (g)
  int bf_ = bid / 64;
  int bg = bid % 64;
  int f0 = bf_ * 64, g0 = bg * 64;
  int tid = threadIdx.x;
#pragma unroll
  for (int s = 0; s < 16; ++s) {
    int idx = s * 256 + tid;
    int fl = idx >> 6, gl = idx & 63;
    tile[fl][gl] = w[(size_t)(f0 + fl) * 4096 + g0 + gl];
  }
  __syncthreads();
#pragma unroll
  for (int s = 0; s < 16; ++s) {
    int idx = s * 256 + tid;
    int gl = idx >> 6, fl = idx & 63;
    wxT[(size_t)(g0 + gl) * 2048 + f0 + fl] = f2bf(tile[fl][gl]);
  }
}

// ---------------------------------------------------------------------------
// Kernel 3: zx = xs @ wx -> bf16 [8192][4096]. 128x128 tile, BK=32, 4 waves.
// ---------------------------------------------------------------------------
__global__ __launch_bounds__(256) void gemm_zx(
    const unsigned short* __restrict__ xs, const unsigned short* __restrict__ wxT,
    unsigned short* __restrict__ zxo) {
  __shared__ uint4 lds[1024];   // A: bytes [0,8192), B: [8192,16384)
  char* ldsb = (char*)lds;
  int bid = blockIdx.x;
  int by = bid >> 5;
  int bx = bid & 31;
  int tid = threadIdx.x, lane = tid & 63, wid = tid >> 6;
  int wr = wid >> 1, wc = wid & 1;
  const int arow0 = by * 128, bcol0 = bx * 128;

  f32x4 acc[4][4] = {};

  for (int kt = 0; kt < 64; ++kt) {
    int k0 = kt * 32;
#pragma unroll
    for (int s = 0; s < 2; ++s) {
      int c = tid + 256 * s;
      int L = c * 16;
      int P = L ^ (((L >> 6) & 7) << 4);
      int row = c >> 2, ko = (c & 3) * 8;
      uint4 av = *(const uint4*)(xs  + (size_t)(arow0 + row) * 2048 + k0 + ko);
      uint4 bv = *(const uint4*)(wxT + (size_t)(bcol0 + row) * 2048 + k0 + ko);
      *(uint4*)(ldsb + P) = av;
      *(uint4*)(ldsb + 8192 + P) = bv;
    }
    __syncthreads();

    bf16x8 afr[4], bfr[4];
#pragma unroll
    for (int i = 0; i < 4; ++i) {
      int arow = wr * 64 + i * 16 + (lane & 15);
      int L = arow * 64 + (lane >> 4) * 16;
      int P = L ^ ((arow & 7) << 4);
      afr[i] = *(bf16x8*)(ldsb + P);
      int brow = wc * 64 + i * 16 + (lane & 15);
      int L2 = brow * 64 + (lane >> 4) * 16;
      int P2 = L2 ^ ((brow & 7) << 4);
      bfr[i] = *(bf16x8*)(ldsb + 8192 + P2);
    }
#pragma unroll
    for (int mi = 0; mi < 4; ++mi)
#pragma unroll
      for (int ni = 0; ni < 4; ++ni)
        acc[mi][ni] = __builtin_amdgcn_mfma_f32_16x16x32_bf16(
            afr[mi], bfr[ni], acc[mi][ni], 0, 0, 0);
    __syncthreads();
  }

#pragma unroll
  for (int mi = 0; mi < 4; ++mi)
#pragma unroll
    for (int ni = 0; ni < 4; ++ni)
#pragma unroll
      for (int r = 0; r < 4; ++r) {
        int rrow = arow0 + wr * 64 + mi * 16 + (lane >> 4) * 4 + r;
        int col  = bcol0 + wc * 64 + ni * 16 + (lane & 15);
        zxo[(size_t)rrow * 4096 + col] = f2bf(acc[mi][ni][r]);
      }
}

// ---------------------------------------------------------------------------
// Kernel 3.5: clear hcom tags (aliases dead xs region; runs after gemm).
// ---------------------------------------------------------------------------
__global__ __launch_bounds__(256) void clear_hcom(uint4* __restrict__ p) {
  p[(size_t)blockIdx.x * 256 + threadIdx.x] = uint4{0, 0, 0, 0};
}

// ---------------------------------------------------------------------------
// Kernel 4: persistent recurrent LSTM. 128 blocks (64/dir) x 1024 threads.
// h exchange: ONE packed u32 per element ((t+1)<<16 | bf16(h)), agent-scope
// relaxed store; consumer poll IS the data load (single IF trip per step).
// W_h pinned in VGPRs via asm identity (R2 showed compiler reloads from L2).
// ---------------------------------------------------------------------------
__device__ __forceinline__ float sigm(float x) {
  return 1.0f / (1.0f + __expf(-x));
}
__device__ __forceinline__ float tanh_fast(float x) {
  float e = __expf(-2.0f * x);
  return (1.0f - e) / (1.0f + e);
}

__global__ __launch_bounds__(1024, 4) void lstm_rec(
    const unsigned short* __restrict__ zx,  // [2][4096][4096] bf16
    const float* __restrict__ w,            // [3072][4096] f32 (w_h = rows 2048+)
    float* __restrict__ hout,               // d_out [2][4096][1024] f32
    unsigned* __restrict__ hcom) {          // [2][4096][1024] packed tag|bf16h
  __shared__ float4 h4[16][16];             // per-wave 64 f32 h slice
  __shared__ float part[2][16][64];         // parity-double-buffered partials

  int bid = blockIdx.x;
  int dir = bid >> 6;
  int bslot = bid & 63;
  int jbase = bslot << 4;                   // 16 j's per block
  int tid = threadIdx.x;
  int wave = tid >> 6;                      // k-slice: wave*64..+63
  int lane = tid & 63;                      // column: jj = lane&15, gate = lane>>4
  int jj = lane & 15, g = lane >> 4;
  int gcol = (g << 10) + jbase + jj;

  // preload W_h slice: w[(2048 + wave*64 + p)][gcol]  (f32, exact)
  float wreg[64];
#pragma unroll
  for (int p = 0; p < 64; ++p)
    wreg[p] = w[(size_t)(2048 + wave * 64 + p) * 4096 + gcol];
  // pin in VGPRs: forbid rematerialization from global
#pragma unroll
  for (int p = 0; p < 64; ++p) asm volatile("" : "+v"(wreg[p]));

  float c_reg = 0.0f;
  const unsigned short* zrow = zx + (size_t)dir * T_STEPS * 4096;
  float* hrow = hout + (size_t)dir * T_STEPS * HDIM;
  unsigned* hcd = hcom + (size_t)dir * T_STEPS * HDIM;

  for (int t = 0; t < T_STEPS; ++t) {
    // wave15 owns the zx contribution (keeps wave0's critical path short)
    float zxv = 0.0f;
    if (wave == 15) zxv = bf2f(zrow[(size_t)t * 4096 + gcol]);

    // poll own 64-element k-slice of h_{t-1}; the poll IS the h load
    float hv = 0.0f;
    if (t > 0) {
      const unsigned* hp = hcd + (size_t)(t - 1) * HDIM + wave * 64 + lane;
      unsigned want = (unsigned)t << 16;    // stored tag = (t-1)+1
      unsigned v;
      do {
        v = __hip_atomic_load(hp, __ATOMIC_RELAXED, __HIP_MEMORY_SCOPE_AGENT);
      } while ((v & 0xffff0000u) != want);
      hv = __builtin_bit_cast(float, v << 16);
    }
    ((float*)&h4[wave][0])[lane] = hv;
    asm volatile("s_waitcnt lgkmcnt(0)" ::: "memory");

    // per-wave partial dot: 64 FMA over broadcast LDS reads
    float a0 = 0.f, a1 = 0.f, a2 = 0.f, a3 = 0.f;
#pragma unroll
    for (int q = 0; q < 16; ++q) {
      float4 x = h4[wave][q];
      a0 = fmaf(wreg[4 * q + 0], x.x, a0);
      a1 = fmaf(wreg[4 * q + 1], x.y, a1);
      a2 = fmaf(wreg[4 * q + 2], x.z, a2);
      a3 = fmaf(wreg[4 * q + 3], x.w, a3);
    }
    float psum = (a0 + a1) + (a2 + a3);
    if (wave == 15) psum += zxv;
    part[t & 1][wave][lane] = psum;
    __syncthreads();   // the ONE barrier per step

    // wave0: reduce, gates (nonlin distributed over all 64 lanes), store
    if (wave == 0) {
      float z = 0.f;
#pragma unroll
      for (int q = 0; q < 16; ++q) z += part[t & 1][q][lane];
      float gz = (g == 2) ? z + 1.0f : z;       // FORGET_BIAS on f gate
      float nl = (g == 1) ? tanh_fast(z) : sigm(gz);
      float iv = __shfl(nl, jj, 64);
      float cv = __shfl(nl, 16 + jj, 64);
      float fv = __shfl(nl, 32 + jj, 64);
      float ov = __shfl(nl, 48 + jj, 64);
      if (lane < 16) {
        float cs = fmaf(fv, c_reg, iv * cv);
        cs = fminf(3.0f, fmaxf(-3.0f, cs));     // CELL_CLIP
        c_reg = cs;
        float h = ov * tanh_fast(cs);
        if (t + 1 < T_STEPS) {
          unsigned pk = ((unsigned)(t + 1) << 16) | (unsigned)f2bf(h);
          __hip_atomic_store(&hcd[(size_t)t * HDIM + jbase + lane], pk,
                             __ATOMIC_RELAXED, __HIP_MEMORY_SCOPE_AGENT);
        }
        hrow[(size_t)t * HDIM + jbase + lane] = h;   // f32 output (write-only)
      }
    }
    // no trailing barrier: part is parity-double-buffered; the global tag
    // chain orders wave0's reads vs other blocks' next-step writes.
  }
}

// ---------------------------------------------------------------------------
// launch
// ---------------------------------------------------------------------------
extern "C" void kernel_launch(void* const* d_in, const int* in_sizes, int n_in,
                              void* d_out, int out_size, void* d_ws, size_t ws_size,
                              hipStream_t stream) {
  const float* rf = (const float*)d_in[0];   // res_for_1  [1][4096][1024]
  const float* rb = (const float*)d_in[1];   // res_back_1 [1][4096][1024]
  const float* w  = (const float*)d_in[2];   // w [3072][4096]
  float* out = (float*)d_out;                // [2][4096][1024]

  char* ws = (char*)d_ws;
  unsigned short* zx  = (unsigned short*)ws;                          // [0, 64 MiB)
  unsigned short* xs  = (unsigned short*)(ws + (64u << 20));          // [64, 96 MiB)
  unsigned*      hcom = (unsigned*)(ws + (64u << 20));                // aliases xs (xs dead after gemm)
  unsigned short* wxT = (unsigned short*)(ws + (96u << 20));          // [96, 112 MiB)

  build_xs<<<16384, 256, 0, stream>>>(rf, rb, xs);
  transpose_wx<<<2048, 256, 0, stream>>>(w, wxT);
  gemm_zx<<<2048, 256, 0, stream>>>(xs, wxT, zx);
  clear_hcom<<<8192, 256, 0, stream>>>((uint4*)hcom);   // zero tags, stream-ordered
  lstm_rec<<<128, 1024, 0, stream>>>(zx, w, out, hcom);
}